// Round 4
// baseline (438.859 us; speedup 1.0000x reference)
//
#include <hip/hip_runtime.h>

// GRU via fp16 MFMA, fp32 accumulate. T=512, B=1024, I=H=64.
// 64 blocks x 256 threads (4 waves). Block owns 16 batch rows; wave w owns
// hidden units [16w,16w+16). Latency-bound regime (1 wave/SIMD, 64 CUs):
// wall time = 512 x per-step critical path. Round 4 shortens the chain:
//   - x-side and h-side gate contributions accumulate in SEPARATE MFMA accs
//     (h-chain = 2 dependent MFMAs instead of 4); merged with 8 VALU adds.
//   - x-acc for step t+1 is computed during step t (cvt + 6 independent
//     MFMAs) -- fills the ds_read-h shadow / combine window, off the path.
//   - program order: ds_read h first, then x-work, then h-MFMAs (lgkmcnt
//     wait lands right before the first h-MFMA), combine, write, one
//     s_barrier per step. X prefetch 2 steps deep, never drained.
// C-layout (verified R3): col(unit)=lane&15, row(batch)=(lane>>4)*4+reg.

typedef _Float16 half8 __attribute__((ext_vector_type(8)));
typedef float    f32x4 __attribute__((ext_vector_type(4)));

#define T_STEPS 512
#define BATCH   1024

struct XBuf { float4 a0, a1, b0, b1; };

__device__ __forceinline__ half8 cvt8(const float4& a, const float4& b) {
    half8 h;
    h[0] = (_Float16)a.x; h[1] = (_Float16)a.y; h[2] = (_Float16)a.z; h[3] = (_Float16)a.w;
    h[4] = (_Float16)b.x; h[5] = (_Float16)b.y; h[6] = (_Float16)b.z; h[7] = (_Float16)b.w;
    return h;
}

__device__ __forceinline__ half8 loadw8(const float* p) {
    const float4* q = (const float4*)p;
    float4 a = q[0], b = q[1];
    return cvt8(a, b);
}

__device__ __forceinline__ void block_sync() {
    asm volatile("s_waitcnt lgkmcnt(0)" ::: "memory");
    __builtin_amdgcn_s_barrier();
    asm volatile("" ::: "memory");
}

#define MFMA16(A, B, C) __builtin_amdgcn_mfma_f32_16x16x32_f16((A), (B), (C), 0, 0, 0)

__global__ __launch_bounds__(256, 1)
void gru_mfma_kernel(const float* __restrict__ X,     // [T,B,64]
                     const float* __restrict__ W_ih,  // [192,64]
                     const float* __restrict__ W_hh,  // [192,64]
                     const float* __restrict__ b_ih,  // [192]
                     const float* __restrict__ b_hh,  // [192]
                     float* __restrict__ out)         // [T*B*64] ++ [B*64]
{
    const int tid   = threadIdx.x;
    const int w     = tid >> 6;        // wave: units [16w,16w+16)
    const int l     = tid & 63;
    const int c     = l & 15;          // A-row / B-col / C-col
    const int g4    = l >> 4;          // lane group (k-slot / C-row group)
    const int u     = w * 16 + c;      // this lane's hidden-unit column
    const int row   = c;               // A-fragment row (batch row within tile)
    const int brow0 = blockIdx.x * 16;

    __shared__ __align__(16) _Float16 hbuf[2][16][72];  // stride 72

    // ---- B-fragments (W columns), fp16, loaded once ----
    // x-side frags (K=64 over input dim), h-side frags (K=64 over h dim).
    const half8 Brx0 = loadw8(W_ih + (u)       * 64 +  0 + 8 * g4);
    const half8 Brx1 = loadw8(W_ih + (u)       * 64 + 32 + 8 * g4);
    const half8 Brh0 = loadw8(W_hh + (u)       * 64 +  0 + 8 * g4);
    const half8 Brh1 = loadw8(W_hh + (u)       * 64 + 32 + 8 * g4);
    const half8 Bzx0 = loadw8(W_ih + (64 + u)  * 64 +  0 + 8 * g4);
    const half8 Bzx1 = loadw8(W_ih + (64 + u)  * 64 + 32 + 8 * g4);
    const half8 Bzh0 = loadw8(W_hh + (64 + u)  * 64 +  0 + 8 * g4);
    const half8 Bzh1 = loadw8(W_hh + (64 + u)  * 64 + 32 + 8 * g4);
    const half8 Bnx0 = loadw8(W_ih + (128 + u) * 64 +  0 + 8 * g4);
    const half8 Bnx1 = loadw8(W_ih + (128 + u) * 64 + 32 + 8 * g4);
    const half8 Bnh0 = loadw8(W_hh + (128 + u) * 64 +  0 + 8 * g4);
    const half8 Bnh1 = loadw8(W_hh + (128 + u) * 64 + 32 + 8 * g4);

    const float rb  = b_ih[u]        + b_hh[u];
    const float zb  = b_ih[64 + u]   + b_hh[64 + u];
    const float nxb = b_ih[128 + u];
    const float nhb = b_hh[128 + u];

    f32x4 hp = {0.f, 0.f, 0.f, 0.f};   // h in C-layout: row 4*g4+i, col u

#define ISSUE_X(XB, T) do {                                                   \
        const float* px_ = X + ((T) * BATCH + brow0 + row) * 64 + 8 * g4;     \
        (XB).a0 = ((const float4*)px_)[0];                                    \
        (XB).a1 = ((const float4*)px_)[1];                                    \
        const float* py_ = px_ + 32;                                          \
        (XB).b0 = ((const float4*)py_)[0];                                    \
        (XB).b1 = ((const float4*)py_)[1];                                    \
    } while (0)

    XBuf xb0, xb1;
    ISSUE_X(xb0, 0);
    ISSUE_X(xb1, 1);

    // zero h(t=0) buffer
    for (int k = tid; k < 2 * 16 * 72; k += 256)
        ((_Float16*)hbuf)[k] = (_Float16)0.f;

    // x-acc for t=0 (from xb0; xb0 becomes free and is refilled at step 0)
    f32x4 axr = {rb, rb, rb, rb};
    f32x4 axz = {zb, zb, zb, zb};
    f32x4 axn = {nxb, nxb, nxb, nxb};
    {
        const half8 x0 = cvt8(xb0.a0, xb0.a1);
        const half8 x1 = cvt8(xb0.b0, xb0.b1);
        axr = MFMA16(x0, Brx0, axr); axr = MFMA16(x1, Brx1, axr);
        axz = MFMA16(x0, Bzx0, axz); axz = MFMA16(x1, Bzx1, axz);
        axn = MFMA16(x0, Bnx0, axn); axn = MFMA16(x1, Bnx1, axn);
    }
    __syncthreads();

    // STEP(t, XA, XB): entry invariants: axr/axz/axn hold x-acc(t);
    // XB holds x(t+1) floats; XA is free (its x(t) was consumed at t-1).
    // Does: h-side MFMAs for t, builds x-acc(t+1) from XB, refills XA<-x(t+2).
#define STEP(T, XA, XB) do {                                                  \
        const int p_ = (T) & 1;                                               \
        /* issue h reads first (latency hidden under x-work below) */         \
        const half8 hf0 = *(const half8*)&hbuf[p_][row][8 * g4];              \
        const half8 hf1 = *(const half8*)&hbuf[p_][row][32 + 8 * g4];         \
        /* x-side for t+1: independent, fills the ds_read/combine shadow */   \
        const half8 nxf0 = cvt8((XB).a0, (XB).a1);                            \
        const half8 nxf1 = cvt8((XB).b0, (XB).b1);                            \
        f32x4 naxr = {rb, rb, rb, rb};                                        \
        f32x4 naxz = {zb, zb, zb, zb};                                        \
        f32x4 naxn = {nxb, nxb, nxb, nxb};                                    \
        naxr = MFMA16(nxf0, Brx0, naxr); naxr = MFMA16(nxf1, Brx1, naxr);     \
        naxz = MFMA16(nxf0, Bzx0, naxz); naxz = MFMA16(nxf1, Bzx1, naxz);     \
        naxn = MFMA16(nxf0, Bnx0, naxn); naxn = MFMA16(nxf1, Bnx1, naxn);     \
        { int tn_ = (T) + 2; if (tn_ > T_STEPS - 1) tn_ = T_STEPS - 1;        \
          ISSUE_X(XA, tn_); }                                                 \
        /* h-side: chain of 2 dependent MFMAs per gate */                     \
        f32x4 hr  = {0.f, 0.f, 0.f, 0.f};                                     \
        f32x4 hz  = {0.f, 0.f, 0.f, 0.f};                                     \
        f32x4 hnh = {nhb, nhb, nhb, nhb};                                     \
        hr  = MFMA16(hf0, Brh0, hr);   hr  = MFMA16(hf1, Brh1, hr);           \
        hz  = MFMA16(hf0, Bzh0, hz);   hz  = MFMA16(hf1, Bzh1, hz);           \
        hnh = MFMA16(hf0, Bnh0, hnh);  hnh = MFMA16(hf1, Bnh1, hnh);          \
        _Pragma("unroll")                                                     \
        for (int i = 0; i < 4; ++i) {                                         \
            const float crv = axr[i] + hr[i];                                 \
            const float czv = axz[i] + hz[i];                                 \
            const float rv = __builtin_amdgcn_rcpf(1.f + __expf(-crv));       \
            const float zv = __builtin_amdgcn_rcpf(1.f + __expf(-czv));       \
            const float npre = fmaf(rv, hnh[i], axn[i]);                      \
            const float nv =                                                  \
                1.f - 2.f * __builtin_amdgcn_rcpf(1.f + __expf(2.f * npre));  \
            const float hn = fmaf(zv, hp[i] - nv, nv);                        \
            hp[i] = hn;                                                       \
            hbuf[p_ ^ 1][4 * g4 + i][u] = (_Float16)hn;                       \
            out[((T) * BATCH + brow0 + 4 * g4 + i) * 64 + u] = hn;            \
        }                                                                     \
        axr = naxr; axz = naxz; axn = naxn;                                   \
        block_sync();                                                         \
    } while (0)

    #pragma unroll 1
    for (int t = 0; t < T_STEPS; t += 2) {
        STEP(t, xb0, xb1);      // consumes xb1=x(t+1), refills xb0<-x(t+2)
        STEP(t + 1, xb1, xb0);  // consumes xb0=x(t+2), refills xb1<-x(t+3)
    }

    #pragma unroll
    for (int i = 0; i < 4; ++i)
        out[T_STEPS * BATCH * 64 + (brow0 + 4 * g4 + i) * 64 + u] = hp[i];

#undef STEP
#undef ISSUE_X
}

extern "C" void kernel_launch(void* const* d_in, const int* in_sizes, int n_in,
                              void* d_out, int out_size, void* d_ws, size_t ws_size,
                              hipStream_t stream) {
    const float* X    = (const float*)d_in[0];
    const float* W_ih = (const float*)d_in[1];
    const float* W_hh = (const float*)d_in[2];
    const float* b_ih = (const float*)d_in[3];
    const float* b_hh = (const float*)d_in[4];
    float* out = (float*)d_out;

    dim3 grid(BATCH / 16);   // 64 blocks
    dim3 block(256);         // 4 waves
    gru_mfma_kernel<<<grid, block, 0, stream>>>(X, W_ih, W_hh, b_ih, b_hh, out);
}